// Round 1
// 20504.568 us; speedup vs baseline: 1.3791x; 1.3791x over previous
//
#include <hip/hip_runtime.h>

// ---- problem constants ----
#define RPB 4            // batch rows per block
// ws layout (float offsets) — sizes identical to previous version, contents re-tiled
#define WS_WCAT   0                       // scan1 gates W: [96][1024][4] k4-tiled, col=u*4+q
#define WS_LINT   (WS_WCAT + 96*4096)     // scan1 lin  W: [40][1024][4] k4-tiled, col=s*8+n
#define WS_BZ     (WS_LINT + 40*4096)     // [1024] combined wlstm bias, col=u*4+q
#define WS_LINB   (WS_BZ + 1024)          // [1024] lin_b, col = s*8+n
#define WS_MU0    (WS_LINB + 1024)        // [128]
#define WS_SEXP   (WS_MU0 + 128)          // [128] exp(0.5*ls0)
#define WS_RNNT   (WS_SEXP + 128)         // scan2 gates W: [128][1024][4] k4-tiled
#define WS_BRNN   (WS_RNNT + 128*4096)    // [1024]
#define WS_PPT1   (WS_BRNN + 1024)        // [24][256][4] k4-tiled
#define WS_PPT2   (WS_PPT1 + 24*1024)     // [64][256][4] k4-tiled

// out offsets (return order, flat)
#define OUT_OBS_MU 0
#define OUT_OBS_S  (256*1024*64)
#define OUT_HPOST  (2*256*1024*64)
#define OUT_CPOST  (OUT_HPOST + 1024*256)
#define OUT_WH     (OUT_CPOST + 1024*256)
#define OUT_WC     (OUT_WH + 1024*256)
#define OUT_WMAP   (OUT_WC + 1024*256)

__device__ __forceinline__ float sigm(float x){ return 1.0f/(1.0f+__expf(-x)); }
// overflow-safe tanh
__device__ __forceinline__ float tanhf_fast(float x){ return 2.0f/(1.0f+__expf(-2.0f*x)) - 1.0f; }

// ---------------- prep kernels ----------------
// scan1 gate weights: ws[k4*4096 + col*4 + j] = W[k4*4+j][col], col=u*4+q, K=384=[state|h]
__global__ void prep_wcat(const float* __restrict__ Wih, const float* __restrict__ Whh,
                          float* __restrict__ ws){
    int idx = blockIdx.x*256 + threadIdx.x;          // < 96*4096
    int k4 = idx >> 12, rem = idx & 4095;
    int col = rem >> 2, j = rem & 3;
    int k = (k4 << 2) | j;
    int u = col >> 2, q = col & 3;                   // PyTorch gate order i,f,g,o
    float v = (k < 128) ? Wih[(q*256+u)*128 + k] : Whh[(q*256+u)*256 + (k-128)];
    ws[WS_WCAT + idx] = v;
}
__global__ void prep_lin(const float* __restrict__ lin_W, float* __restrict__ ws){
    int idx = blockIdx.x*256 + threadIdx.x;          // < 40*4096
    int k4 = idx >> 12, rem = idx & 4095;
    int col = rem >> 2, j = rem & 3;
    int k = (k4 << 2) | j;
    int s = col >> 3, n = col & 7;
    ws[WS_LINT + idx] = lin_W[(n*128 + s)*160 + k];
}
__global__ void prep_rnn(const float* __restrict__ Wih, const float* __restrict__ Whh,
                         float* __restrict__ ws){
    int idx = blockIdx.x*256 + threadIdx.x;          // < 128*4096
    int k4 = idx >> 12, rem = idx & 4095;
    int col = rem >> 2, j = rem & 3;
    int k = (k4 << 2) | j;
    int u = col >> 2, q = col & 3;
    float v = (k < 256) ? Wih[(q*256+u)*256 + k] : Whh[(q*256+u)*256 + (k-256)];
    ws[WS_RNNT + idx] = v;
}
__global__ void prep_bias(const float* __restrict__ wbih, const float* __restrict__ wbhh,
                          const float* __restrict__ rbih, const float* __restrict__ rbhh,
                          const float* __restrict__ lin_b, float* __restrict__ ws){
    int idx = blockIdx.x*256 + threadIdx.x;          // < 1024
    int u = idx >> 2, q = idx & 3;
    ws[WS_BZ + idx]   = wbih[q*256+u] + wbhh[q*256+u];
    ws[WS_BRNN + idx] = rbih[q*256+u] + rbhh[q*256+u];
    int s = idx >> 3, n = idx & 7;
    ws[WS_LINB + idx] = lin_b[n*128 + s];
}
__global__ void prep_pp(const float* __restrict__ W1, const float* __restrict__ W2,
                        float* __restrict__ ws){
    int idx = blockIdx.x*256 + threadIdx.x;          // < 24*1024 + 64*1024
    if (idx < 24*1024){
        int k4 = idx >> 10, rem = idx & 1023;
        int i = rem >> 2, j = rem & 3;
        ws[WS_PPT1 + idx] = W1[i*96 + (k4*4 + j)];
    } else {
        int kk = idx - 24*1024;
        int k4 = kk >> 10, rem = kk & 1023;
        int i = rem >> 2, j = rem & 3;
        ws[WS_PPT2 + kk] = W2[i*256 + (k4*4 + j)];
    }
}
// initial DBlock on the single broadcast h0 row
__global__ void dblock0(const float* __restrict__ h0,
                        const float* __restrict__ W1, const float* __restrict__ b1,
                        const float* __restrict__ W2, const float* __restrict__ b2,
                        const float* __restrict__ Wmu, const float* __restrict__ bmu,
                        const float* __restrict__ Wls, const float* __restrict__ bls,
                        float* __restrict__ ws){
    __shared__ float s_t[512];
    __shared__ float s_h[256];
    int tid = threadIdx.x;                            // 512 threads
    if (tid < 256) s_h[tid] = h0[tid];
    __syncthreads();
    {
        float a = b1[tid], b = b2[tid];
        for (int i=0;i<256;i++){ float h = s_h[i]; a += h*W1[tid*256+i]; b += h*W2[tid*256+i]; }
        s_t[tid] = tanhf_fast(a)*sigm(b);
    }
    __syncthreads();
    if (tid < 128){
        float m = bmu[tid];
        for (int k=0;k<512;k++) m += s_t[k]*Wmu[tid*512+k];
        ws[WS_MU0 + tid] = m;
    } else if (tid < 256){
        int j = tid - 128;
        float l = bls[j];
        for (int k=0;k<512;k++) l += s_t[k]*Wls[j*512+k];
        ws[WS_SEXP + j] = __expf(0.5f*l);
    }
}

// ---------------- scan 1: weight-LSTM + combinational linears + emission ----------------
// 1024 threads = 16 waves/CU (4/SIMD). Output-column partition keeps L2 weight
// traffic identical to the 256-thread version while 4x-ing latency hiding.
__global__ __launch_bounds__(1024, 4) void scan1_kernel(
    const float* __restrict__ ext, const float* __restrict__ eps_init,
    const float* __restrict__ eps_seq, const float* __restrict__ eps_obs,
    const float* __restrict__ dyn_h0,
    const float* __restrict__ wl_W, const float* __restrict__ wl_b,
    const float* __restrict__ dyn_logsigma,
    const float* __restrict__ est_logdelta, const float* __restrict__ est_H,
    const float* __restrict__ est_b,
    const float* __restrict__ ws, float* __restrict__ out)
{
    const int tid = threadIdx.x;
    const int r0  = blockIdx.x * RPB;
    const int u   = tid & 255;     // unit (cell phase)
    const int rr  = tid >> 8;      // row  (cell phase)

    __shared__ __align__(16) float s_x[RPB][384];    // [state(128) | h(256)]
    __shared__ __align__(16) float s_xc[RPB][160];   // [state(128) | u(32)]
    __shared__ __align__(16) float s_g[RPB][1024];   // gate pre-activations
    __shared__ __align__(16) float s_mus[RPB][1024]; // mus, col = s*8+n
    __shared__ __align__(16) float s_HT[128][64];    // H^T [s][o]
    __shared__ __align__(16) float s_wlW[2048];      // wl_W staged
    __shared__ float s_pe[4][RPB][64];               // emission split-K partials
    __shared__ float s_w[RPB][8];
    __shared__ float s_wlog[RPB][8];
    __shared__ float s_dstd[128];
    __shared__ float s_ostd[64], s_eb[64], s_wlb[8];

    for (int idx = tid; idx < 128*64; idx += 1024){
        int s = idx >> 6, o = idx & 63;
        s_HT[s][o] = est_H[o*128 + s];
    }
    for (int idx = tid; idx < 2048; idx += 1024) s_wlW[idx] = wl_W[idx];
    if (tid < 128) s_dstd[tid] = __expf(0.5f*dyn_logsigma[tid]);
    if (tid < 64){ s_ostd[tid] = __expf(0.5f*est_logdelta[tid]); s_eb[tid] = est_b[tid]; }
    if (tid < 8) s_wlb[tid] = wl_b[tid];
    if (tid < 128){
        float m = ws[WS_MU0+tid], sd = ws[WS_SEXP+tid];
        #pragma unroll
        for (int r=0;r<RPB;r++){
            float v = m + sd*eps_init[(r0+r)*128 + tid];
            s_x[r][tid] = v; s_xc[r][tid] = v;
        }
    }
    if (tid < 256){
        float h0v = dyn_h0[tid];
        #pragma unroll
        for (int r=0;r<RPB;r++) s_x[r][128+tid] = h0v;
    }
    float c_reg = 0.0f;                               // c for (u, rr)
    const float bz = ws[WS_BZ + tid];
    const float lb = ws[WS_LINB + tid];
    const float4* __restrict__ Wg = (const float4*)(ws + WS_WCAT);
    const float4* __restrict__ Lg = (const float4*)(ws + WS_LINT);
    __syncthreads();

    for (int t = 0; t < 256; t++){
        // ---- gates GEMV: thread = output col (u*4+q), K=384; x via LDS broadcast ----
        float ac[RPB];
        #pragma unroll
        for (int r=0;r<RPB;r++) ac[r] = bz;
        for (int i4 = 0; i4 < 96; i4++){
            float4 w = Wg[i4*1024 + tid];
            #pragma unroll
            for (int r=0;r<RPB;r++){
                float4 xv = ((const float4*)s_x[r])[i4];
                ac[r] += xv.x*w.x + xv.y*w.y + xv.z*w.z + xv.w*w.w;
            }
        }
        #pragma unroll
        for (int r=0;r<RPB;r++) s_g[r][tid] = ac[r];
        __syncthreads();

        // ---- LSTM cell: thread = (u, rr); also stage u(t) into s_xc ----
        {
            const float4 g = *(const float4*)&s_g[rr][u*4];
            float ig = sigm(g.x), fg = sigm(g.y);
            float gg = tanhf_fast(g.z), og = sigm(g.w);
            float c = fg*c_reg + ig*gg;
            c_reg = c;
            s_x[rr][128+u] = og*tanhf_fast(c);
        }
        if (tid < RPB*32){
            int r = tid >> 5, ii = tid & 31;
            s_xc[r][128+ii] = ext[(t*1024 + r0 + r)*32 + ii];
        }
        __syncthreads();

        // ---- wl logits: (rr, n, part) split-K=8, shuffle-reduce over 32 lanes ----
        {
            int n = (tid >> 5) & 7, part = tid & 31;
            const float* wrow = &s_wlW[n*256 + part*8];
            const float* hrow = &s_x[rr][128 + part*8];
            float p = 0.f;
            #pragma unroll
            for (int ii=0; ii<8; ii++) p += hrow[ii]*wrow[ii];
            p += __shfl_xor(p, 1);
            p += __shfl_xor(p, 2);
            p += __shfl_xor(p, 4);
            p += __shfl_xor(p, 8);
            p += __shfl_xor(p, 16);
            if (part == 0) s_wlog[rr][n] = p + s_wlb[n];
        }
        __syncthreads();

        // ---- softmax (tid<4, cheap) overlapped with mus GEMV (all threads) ----
        if (tid < 4){
            float mx = -1e30f;
            #pragma unroll
            for (int n=0;n<8;n++) mx = fmaxf(mx, s_wlog[tid][n]);
            float e[8]; float sum = 0.0f;
            #pragma unroll
            for (int n=0;n<8;n++){ e[n] = __expf(s_wlog[tid][n]-mx); sum += e[n]; }
            float inv = 1.0f/sum;
            #pragma unroll
            for (int n=0;n<8;n++) s_w[tid][n] = e[n]*inv;
        }
        float am[RPB];
        #pragma unroll
        for (int r=0;r<RPB;r++) am[r] = lb;
        for (int i4 = 0; i4 < 40; i4++){
            float4 w = Lg[i4*1024 + tid];
            #pragma unroll
            for (int r=0;r<RPB;r++){
                float4 xv = ((const float4*)s_xc[r])[i4];
                am[r] += xv.x*w.x + xv.y*w.y + xv.z*w.z + xv.w*w.w;
            }
        }
        #pragma unroll
        for (int r=0;r<RPB;r++) s_mus[r][tid] = am[r];
        __syncthreads();

        // ---- weighted combine + resample (512 thr) + wmap write (32 thr) ----
        if (tid < 512){
            int sidx = tid & 127, r = tid >> 7;
            const float* mrow = &s_mus[r][sidx*8];
            const float* wv = s_w[r];
            float mu = mrow[0]*wv[0] + mrow[1]*wv[1] + mrow[2]*wv[2] + mrow[3]*wv[3]
                     + mrow[4]*wv[4] + mrow[5]*wv[5] + mrow[6]*wv[6] + mrow[7]*wv[7];
            float st = mu + s_dstd[sidx]*eps_seq[(t*1024 + r0 + r)*128 + sidx];
            s_x[r][sidx] = st; s_xc[r][sidx] = st;
        } else if (tid < 544){
            int k = tid - 512; int r = k >> 3, n = k & 7;
            out[OUT_WMAP + (t*1024 + r0 + r)*8 + n] = s_w[r][n];
        }
        __syncthreads();

        // ---- emission: split-K partials (all 1024) then reduce (256) ----
        {
            int o = tid & 63, r = (tid >> 6) & 3, kq = tid >> 8;
            const float* xrow = &s_x[r][kq*32];
            float a = 0.f;
            #pragma unroll
            for (int k=0;k<32;k++) a += xrow[k]*s_HT[kq*32+k][o];
            s_pe[kq][r][o] = a;
        }
        __syncthreads();
        if (tid < 256){
            int o = tid & 63, r = tid >> 6;
            float a = s_eb[o] + s_pe[0][r][o] + s_pe[1][r][o]
                    + s_pe[2][r][o] + s_pe[3][r][o];
            int base = (t*1024 + r0 + r)*64 + o;
            out[OUT_OBS_MU + base] = a;
            out[OUT_OBS_S  + base] = a + s_ostd[o]*eps_obs[base];
        }
        // no barrier needed: next writers of s_pe/s_x are separated by >=1 barrier
    }
    out[OUT_WH + (r0+rr)*256 + u] = s_x[rr][128+u];
    out[OUT_WC + (r0+rr)*256 + u] = c_reg;
}

// ---------------- scan 2: fused PreProcess MLP + posterior LSTM ----------------
__global__ __launch_bounds__(1024, 4) void scan2_kernel(
    const float* __restrict__ ext,
    const float* __restrict__ pp_b1, const float* __restrict__ pp_b2,
    const float* __restrict__ posterior_h0,
    const float* __restrict__ ws, float* __restrict__ out)
{
    const int tid = threadIdx.x;
    const int r0  = blockIdx.x * RPB;
    const int u   = tid & 255;
    const int rr  = tid >> 8;

    __shared__ __align__(16) float s_v[RPB][512];    // [px(256) | h(256)]
    __shared__ __align__(16) float s_ax[RPB][96];
    __shared__ __align__(16) float s_l1[RPB][256];
    __shared__ __align__(16) float s_p[4][RPB][256]; // split-K partials
    __shared__ __align__(16) float s_g[RPB][1024];

    float c_reg = 0.0f;
    if (tid < 256){
        float h0v = posterior_h0[tid];
        #pragma unroll
        for (int r=0;r<RPB;r++) s_v[r][256+tid] = h0v;
    }
    const float* __restrict__ obs_s = out + OUT_OBS_S;
    if (tid < RPB*96){                               // stage ax(t=0)
        int r = tid/96, i = tid - r*96;
        int row = r0 + r;
        s_ax[r][i] = (i < 32) ? ext[row*32 + i] : obs_s[row*64 + (i-32)];
    }
    const float b1v = pp_b1[u];
    const float b2v = pp_b2[u];
    const float brz = ws[WS_BRNN + tid];
    const float4* __restrict__ T1g = (const float4*)(ws + WS_PPT1);
    const float4* __restrict__ T2g = (const float4*)(ws + WS_PPT2);
    const float4* __restrict__ Rg  = (const float4*)(ws + WS_RNNT);
    __syncthreads();

    for (int t = 0; t < 256; t++){
        // ---- MLP1 partials: thread = (i=u, kq=rr), K-chunk = 24 ----
        {
            float p[RPB];
            #pragma unroll
            for (int r=0;r<RPB;r++) p[r] = 0.f;
            #pragma unroll
            for (int ii=0; ii<6; ii++){
                int k4 = rr*6 + ii;
                float4 w = T1g[k4*256 + u];
                #pragma unroll
                for (int r=0;r<RPB;r++){
                    float4 xv = ((const float4*)s_ax[r])[k4];
                    p[r] += xv.x*w.x + xv.y*w.y + xv.z*w.z + xv.w*w.w;
                }
            }
            #pragma unroll
            for (int r=0;r<RPB;r++) s_p[rr][r][u] = p[r];
        }
        __syncthreads();
        {   // reduce + ReLU -> l1
            float l1 = b1v + s_p[0][rr][u] + s_p[1][rr][u] + s_p[2][rr][u] + s_p[3][rr][u];
            s_l1[rr][u] = fmaxf(l1, 0.f);
        }
        __syncthreads();
        // ---- MLP2 partials: K-chunk = 64 ----
        {
            float p[RPB];
            #pragma unroll
            for (int r=0;r<RPB;r++) p[r] = 0.f;
            for (int ii=0; ii<16; ii++){
                int k4 = rr*16 + ii;
                float4 w = T2g[k4*256 + u];
                #pragma unroll
                for (int r=0;r<RPB;r++){
                    float4 xv = ((const float4*)s_l1[r])[k4];
                    p[r] += xv.x*w.x + xv.y*w.y + xv.z*w.z + xv.w*w.w;
                }
            }
            #pragma unroll
            for (int r=0;r<RPB;r++) s_p[rr][r][u] = p[r];
        }
        __syncthreads();
        {   // reduce + ReLU -> px
            float l2 = b2v + s_p[0][rr][u] + s_p[1][rr][u] + s_p[2][rr][u] + s_p[3][rr][u];
            s_v[rr][u] = fmaxf(l2, 0.f);
        }
        __syncthreads();
        // ---- gates GEMV (col=tid, K=512) with ax(t+1) staged under it ----
        if (t < 255 && tid < RPB*96){
            int r = tid/96, i = tid - r*96;
            int row = (t+1)*1024 + r0 + r;
            s_ax[r][i] = (i < 32) ? ext[row*32 + i] : obs_s[row*64 + (i-32)];
        }
        float ac[RPB];
        #pragma unroll
        for (int r=0;r<RPB;r++) ac[r] = brz;
        for (int i4 = 0; i4 < 128; i4++){
            float4 w = Rg[i4*1024 + tid];
            #pragma unroll
            for (int r=0;r<RPB;r++){
                float4 xv = ((const float4*)s_v[r])[i4];
                ac[r] += xv.x*w.x + xv.y*w.y + xv.z*w.z + xv.w*w.w;
            }
        }
        #pragma unroll
        for (int r=0;r<RPB;r++) s_g[r][tid] = ac[r];
        __syncthreads();
        // ---- cell: thread = (u, rr) ----
        {
            const float4 g = *(const float4*)&s_g[rr][u*4];
            float ig = sigm(g.x), fg = sigm(g.y);
            float gg = tanhf_fast(g.z), og = sigm(g.w);
            float c = fg*c_reg + ig*gg;
            c_reg = c;
            s_v[rr][256+u] = og*tanhf_fast(c);
        }
        __syncthreads();
    }
    out[OUT_HPOST + (r0+rr)*256 + u] = s_v[rr][256+u];
    out[OUT_CPOST + (r0+rr)*256 + u] = c_reg;
}

extern "C" void kernel_launch(void* const* d_in, const int* in_sizes, int n_in,
                              void* d_out, int out_size, void* d_ws, size_t ws_size,
                              hipStream_t stream) {
    const float* ext          = (const float*)d_in[0];
    const float* eps_init     = (const float*)d_in[1];
    const float* eps_seq      = (const float*)d_in[2];
    const float* eps_obs      = (const float*)d_in[3];
    const float* pp_W1        = (const float*)d_in[4];
    const float* pp_b1        = (const float*)d_in[5];
    const float* pp_W2        = (const float*)d_in[6];
    const float* pp_b2        = (const float*)d_in[7];
    const float* rnn_Wih      = (const float*)d_in[8];
    const float* rnn_Whh      = (const float*)d_in[9];
    const float* rnn_bih      = (const float*)d_in[10];
    const float* rnn_bhh      = (const float*)d_in[11];
    const float* posterior_h0 = (const float*)d_in[12];
    const float* gd_W1        = (const float*)d_in[13];
    const float* gd_b1        = (const float*)d_in[14];
    const float* gd_W2        = (const float*)d_in[15];
    const float* gd_b2        = (const float*)d_in[16];
    const float* gd_Wmu       = (const float*)d_in[17];
    const float* gd_bmu       = (const float*)d_in[18];
    const float* gd_Wls       = (const float*)d_in[19];
    const float* gd_bls       = (const float*)d_in[20];
    const float* dyn_h0       = (const float*)d_in[21];
    const float* wlstm_Wih    = (const float*)d_in[22];
    const float* wlstm_Whh    = (const float*)d_in[23];
    const float* wlstm_bih    = (const float*)d_in[24];
    const float* wlstm_bhh    = (const float*)d_in[25];
    const float* wl_W         = (const float*)d_in[26];
    const float* wl_b         = (const float*)d_in[27];
    const float* lin_W        = (const float*)d_in[28];
    const float* lin_b        = (const float*)d_in[29];
    const float* dyn_logsigma = (const float*)d_in[30];
    const float* est_logdelta = (const float*)d_in[31];
    const float* est_H        = (const float*)d_in[32];
    const float* est_bias     = (const float*)d_in[33];
    float* out = (float*)d_out;
    float* ws  = (float*)d_ws;

    prep_wcat<<<1536, 256, 0, stream>>>(wlstm_Wih, wlstm_Whh, ws);
    prep_lin <<<640,  256, 0, stream>>>(lin_W, ws);
    prep_rnn <<<2048, 256, 0, stream>>>(rnn_Wih, rnn_Whh, ws);
    prep_bias<<<4,    256, 0, stream>>>(wlstm_bih, wlstm_bhh, rnn_bih, rnn_bhh, lin_b, ws);
    prep_pp  <<<352,  256, 0, stream>>>(pp_W1, pp_W2, ws);
    dblock0  <<<1,    512, 0, stream>>>(posterior_h0, gd_W1, gd_b1, gd_W2, gd_b2,
                                        gd_Wmu, gd_bmu, gd_Wls, gd_bls, ws);
    scan1_kernel<<<256, 1024, 0, stream>>>(ext, eps_init, eps_seq, eps_obs, dyn_h0,
                                           wl_W, wl_b, dyn_logsigma, est_logdelta,
                                           est_H, est_bias, ws, out);
    scan2_kernel<<<256, 1024, 0, stream>>>(ext, pp_b1, pp_b2, posterior_h0, ws, out);
}